// Round 21
// baseline (276.502 us; speedup 1.0000x reference)
//
#include <hip/hip_runtime.h>
#include <hip/hip_bf16.h>

typedef __attribute__((ext_vector_type(8))) short short8;
typedef __attribute__((ext_vector_type(4))) short s16x4;
typedef __attribute__((ext_vector_type(4))) float f32x4;
typedef __attribute__((ext_vector_type(16))) float f32x16;

#define MFMA_BF16(A, B, C) __builtin_amdgcn_mfma_f32_16x16x32_bf16(A, B, C, 0, 0, 0)
#define MFMA32(A, B, C) __builtin_amdgcn_mfma_f32_32x32x16_bf16(A, B, C, 0, 0, 0)

// async global->LDS, 16B per lane. LDS dest is wave-uniform base + lane*16.
__device__ __forceinline__ void gload_lds16(const __hip_bfloat16* g, __hip_bfloat16* l) {
  __builtin_amdgcn_global_load_lds(
      (const __attribute__((address_space(1))) unsigned int*)g,
      (__attribute__((address_space(3))) unsigned int*)l, 16, 0, 0);
}

// NaN/Inf tripwire (fast-math-immune): finite -> x, else -> repl.
__device__ __forceinline__ float finite_or(float x, float repl) {
  unsigned u;
  __builtin_memcpy(&u, &x, 4);
  return ((u & 0x7f800000u) == 0x7f800000u) ? repl : x;
}

__device__ __forceinline__ short bf16_bits(float x) {
  __hip_bfloat16 b = __float2bfloat16(x);
  short s;
  __builtin_memcpy(&s, &b, 2);
  return s;
}

__device__ __forceinline__ short8 pack8(f32x4 a, f32x4 b) {
  short8 r;
  r[0] = bf16_bits(a[0]); r[1] = bf16_bits(a[1]);
  r[2] = bf16_bits(a[2]); r[3] = bf16_bits(a[3]);
  r[4] = bf16_bits(b[0]); r[5] = bf16_bits(b[1]);
  r[6] = bf16_bits(b[2]); r[7] = bf16_bits(b[3]);
  return r;
}

// ---------------------------------------------------------------------------
// f32 -> bf16 bulk conversion (unchanged).
// ---------------------------------------------------------------------------
__global__ __launch_bounds__(256) void cvt_kernel(
    const float* x0, const float* x1, const float* x2,
    const float* w0, const float* w1, const float* w2, const float* w3,
    __hip_bfloat16* y0, __hip_bfloat16* y1, __hip_bfloat16* y2,
    __hip_bfloat16* u0, __hip_bfloat16* u1, __hip_bfloat16* u2, __hip_bfloat16* u3)
{
  const int z = blockIdx.y;
  const float* s = z == 0 ? x0 : z == 1 ? x1 : z == 2 ? x2
                 : z == 3 ? w0 : z == 4 ? w1 : z == 5 ? w2 : w3;
  __hip_bfloat16* d = z == 0 ? y0 : z == 1 ? y1 : z == 2 ? y2
                    : z == 3 ? u0 : z == 4 ? u1 : z == 5 ? u2 : u3;
  const size_t n = (z < 3) ? (size_t)8388608 : (size_t)4194304;
  const size_t stride = (size_t)gridDim.x * 256 * 8;
  for (size_t i = ((size_t)blockIdx.x * 256 + threadIdx.x) * 8; i < n; i += stride) {
    f32x4 a = *(const f32x4*)(s + i);
    f32x4 b = *(const f32x4*)(s + i + 4);
    *(short8*)((short*)d + i) = pack8(a, b);
  }
}

// ---------------------------------------------------------------------------
// Pipelined GEMM body (T3+T4): 128x256 tile, BK=64, 8 waves, ring-3 LDS,
// counted vmcnt(6). R17/R19-verified structure (unchanged).
// ---------------------------------------------------------------------------
#define GBUF 24576

__device__ __forceinline__ void stage_A(const __hip_bfloat16* Ab, __hip_bfloat16* bufA,
                                        int kcol, int t, int wave) {
#pragma unroll
  for (int r = 0; r < 2; ++r) {
    const int ci = r * 512 + t;
    const int row = ci >> 3, c = ci & 7;
    const int sc = c ^ (row & 7);
    gload_lds16(Ab + (size_t)row * 2048 + kcol + sc * 8, bufA + r * 4096 + wave * 512);
  }
}
__device__ __forceinline__ void stage_Br(const __hip_bfloat16* Bb, __hip_bfloat16* bufB,
                                         int kcol, int t, int wave, int r) {
  const int ci = r * 512 + t;
  const int row = ci >> 3, c = ci & 7;
  const int sc = c ^ (row & 7);
  gload_lds16(Bb + (size_t)row * 2048 + kcol + sc * 8, bufB + r * 4096 + wave * 512);
}

template <typename OutT, bool BIAS_ROW>
__device__ __forceinline__ void gemm8p_body(
    const __hip_bfloat16* __restrict__ A, const __hip_bfloat16* __restrict__ Bt,
    const float* __restrict__ bias, OutT* __restrict__ C,
    int m0, int n0, int N, float trip, __hip_bfloat16* sm)
{
  constexpr int K = 2048, NT = K / 64;
  const int t = threadIdx.x, wave = t >> 6, lane = t & 63;
  const int ll = lane & 15, lg = lane >> 4;
  const int wmB = (wave >> 2) * 64, wnB = (wave & 3) * 64;
  const __hip_bfloat16* Ab = A + (size_t)m0 * K;
  const __hip_bfloat16* Bb = Bt + (size_t)n0 * K;

  f32x4 acc[4][4] = {};

  stage_A(Ab, sm, 0, t, wave);
  stage_Br(Bb, sm + 8192, 0, t, wave, 0);
  stage_Br(Bb, sm + 8192, 0, t, wave, 1);
  stage_Br(Bb, sm + 8192, 0, t, wave, 2);
  stage_Br(Bb, sm + 8192, 0, t, wave, 3);
  stage_A(Ab, sm + GBUF, 64, t, wave);
  stage_Br(Bb, sm + GBUF + 8192, 64, t, wave, 0);
  stage_Br(Bb, sm + GBUF + 8192, 64, t, wave, 1);
  stage_Br(Bb, sm + GBUF + 8192, 64, t, wave, 2);
  stage_Br(Bb, sm + GBUF + 8192, 64, t, wave, 3);
  asm volatile("s_waitcnt vmcnt(6)" ::: "memory");
  __builtin_amdgcn_s_barrier();

  for (int i = 0; i < NT; ++i) {
    const __hip_bfloat16* bufA = sm + (i % 3) * GBUF;
    const __hip_bfloat16* bufB = bufA + 8192;
    const bool pf = (i + 2 < NT);
    __hip_bfloat16* pA = sm + ((i + 2) % 3) * GBUF;
    const int pk = (i + 2) * 64;

#pragma unroll
    for (int kk = 0; kk < 2; ++kk) {
      short8 af[4], bf[4];
#pragma unroll
      for (int f = 0; f < 4; ++f) {
        const int ar = wmB + f * 16 + ll;
        af[f] = *(const short8*)&bufA[ar * 64 + (((kk * 4 + lg) ^ (ar & 7)) << 3)];
        const int br = wnB + f * 16 + ll;
        bf[f] = *(const short8*)&bufB[br * 64 + (((kk * 4 + lg) ^ (br & 7)) << 3)];
      }
      if (pf) {
        if (kk == 0) {
          stage_A(Ab, pA, pk, t, wave);
          stage_Br(Bb, pA + 8192, pk, t, wave, 0);
        } else {
          stage_Br(Bb, pA + 8192, pk, t, wave, 1);
          stage_Br(Bb, pA + 8192, pk, t, wave, 2);
          stage_Br(Bb, pA + 8192, pk, t, wave, 3);
        }
      }
      asm volatile("s_waitcnt lgkmcnt(0)" ::: "memory");
      __builtin_amdgcn_sched_barrier(0);
      __builtin_amdgcn_s_setprio(1);
#pragma unroll
      for (int mi = 0; mi < 4; ++mi)
#pragma unroll
        for (int ni = 0; ni < 4; ++ni)
          acc[mi][ni] = MFMA_BF16(af[mi], bf[ni], acc[mi][ni]);
      __builtin_amdgcn_s_setprio(0);
      __builtin_amdgcn_sched_barrier(0);
    }

    const int rem = NT - 1 - i;
    if (rem >= 2) {
      asm volatile("s_waitcnt vmcnt(6)" ::: "memory");
      __builtin_amdgcn_s_barrier();
    } else if (rem == 1) {
      asm volatile("s_waitcnt vmcnt(0)" ::: "memory");
      __builtin_amdgcn_s_barrier();
    }
  }

#pragma unroll
  for (int mi = 0; mi < 4; ++mi)
#pragma unroll
    for (int ni = 0; ni < 4; ++ni) {
      const int col = n0 + wnB + ni * 16 + ll;
      const float bcol = BIAS_ROW ? 0.f : bias[col];
#pragma unroll
      for (int j = 0; j < 4; ++j) {
        const int row = m0 + wmB + mi * 16 + lg * 4 + j;
        const float bv = BIAS_ROW ? bias[row] : bcol;
        const float val = finite_or(acc[mi][ni][j] + bv, trip);
        if constexpr (__is_same(OutT, float))
          C[(size_t)row * N + col] = val;
        else
          C[(size_t)row * N + col] = __float2bfloat16(val);
      }
    }
}

// Fused launch: blocks 0..511 = Q,K projections; 512..767 = V^T projection.
__global__ __launch_bounds__(512) void gemm_qkvvt_kernel(
    const __hip_bfloat16* xq, const __hip_bfloat16* xk, const __hip_bfloat16* xv,
    const __hip_bfloat16* Wq, const __hip_bfloat16* Wk, const __hip_bfloat16* Wv,
    const float* bq, const float* bk, const float* bv,
    __hip_bfloat16* Q, __hip_bfloat16* K, __hip_bfloat16* Vt2)
{
  __shared__ __align__(16) __hip_bfloat16 sm[3 * GBUF];
  const int L = (int)blockIdx.x;
  if (L < 512) {
    const int z = L & 1;
    const int r = L >> 1;            // 0..255
    const int n0 = (r & 7) * 256;    // N=2048 -> 8 n-tiles
    const int m0 = (r >> 3) * 128;   // M=4096 -> 32 m-tiles
    gemm8p_body<__hip_bfloat16, false>(z ? xk : xq, z ? Wk : Wq, z ? bk : bq,
                                       z ? K : Q, m0, n0, 2048, 20000.0f, sm);
  } else {
    const int r = L - 512;           // 0..255
    const int n0 = (r & 15) * 256;   // N=4096 -> 16 n-tiles
    const int m0 = (r >> 4) * 128;   // M=2048 -> 16 m-tiles
    gemm8p_body<__hip_bfloat16, true>(Wv, xv, bv, Vt2, m0, n0, 4096, 30000.0f, sm);
  }
}

__global__ __launch_bounds__(512) void gemm_out_kernel(
    const __hip_bfloat16* A, const __hip_bfloat16* W, const float* b, float* C)
{
  __shared__ __align__(16) __hip_bfloat16 sm[3 * GBUF];
  gemm8p_body<float, false>(A, W, b, C, (int)blockIdx.y * 128,
                            (int)blockIdx.x * 256, 2048, 50000.0f, sm);
}

// ---------------------------------------------------------------------------
// Causal flash attention v9: 32x32 MFMA fragments — each wave serves 32 q-rows
// per fragment read (vs 16), halving per-q LDS reads/staging/barriers.
//  - K/V LDS layouts + staging: byte-identical to the verified kernel.
//  - C/D layout (m74/m101-verified): col=lane&31, row=(reg&3)+8(reg>>2)+4(lane>>5).
//  - A/B layout: row/col=lane&31, k=(lane>>5)*8+e (natural analog of 16x16).
//  - softmax per-lane scalar (q=lane&31); row-reduce = one shfl_xor(.,32).
//  - block = 4 waves x 32q = 128 q; 512 blocks (2/CU), qi pair (a,15-a).
// ---------------------------------------------------------------------------
__global__ __launch_bounds__(256) void attn_kernel(
    const __hip_bfloat16* __restrict__ Qb, const __hip_bfloat16* __restrict__ Kb,
    const __hip_bfloat16* __restrict__ Vt, __hip_bfloat16* __restrict__ Ob)
{
  constexpr int S = 2048, D = 2048, HD = 128;
  __shared__ __align__(16) __hip_bfloat16 Ks[64 * 128];  // [kv][d], chunk ^= kv&7
  __shared__ __align__(16) __hip_bfloat16 Vs[128 * 64];  // [d][kv], chunk ^= d&7
  __shared__ __align__(16) short Ps[4][32 * 64];         // P^T [q][k] per wave, chunk ^= q&7

  const int t = threadIdx.x, wave = t >> 6, lane = t & 63;
  const int lq = lane & 31, hi = lane >> 5;
  const int L = (int)blockIdx.x;                   // 0..511
  const int bh = ((L & 7) << 2) | ((L >> 3) & 3);  // XCD-grouped (invariant under +256)
  const int p = L >> 5;                            // 0..15; CU pair gets (a, a+8)
  const int qi = (p < 8) ? p : 23 - p;             // -> qi pair (a, 15-a): uniform work
  const int b = bh >> 4, h = bh & 15;
  const int q0 = qi * 128;
  const int qrow = q0 + wave * 32 + lq;
  char* const Psw = (char*)&Ps[wave][0];

  auto stageKV = [&](int kv0) {
#pragma unroll
    for (int r = 0; r < 4; ++r) {
      const int s = r * 256 + t;
      const int row = s >> 4, ch = s & 15;
      const int sc = ch ^ (row & 7);
      gload_lds16(Kb + (size_t)(b * S + kv0 + row) * D + h * HD + sc * 8,
                  Ks + r * 2048 + wave * 512);
    }
#pragma unroll
    for (int r = 0; r < 4; ++r) {
      const int s = r * 256 + t;
      const int d = s >> 3, ch = s & 7;
      const int sc = ch ^ (d & 7);
      gload_lds16(Vt + (size_t)(h * HD + d) * (2 * S) + b * S + kv0 + sc * 8,
                  Vs + r * 2048 + wave * 512);
    }
  };

  // Q fragments (B-operand): col q=lq, k = step*16 + hi*8 + e over d=0..127
  short8 qf[8];
  const __hip_bfloat16* qptr = Qb + (size_t)(b * S + qrow) * D + h * HD + hi * 8;
#pragma unroll
  for (int s = 0; s < 8; ++s) qf[s] = *(const short8*)(qptr + s * 16);

  f32x16 oacc[4] = {};
  float mrun = -1e30f, lrun = 0.f;

  const int NT = 2 * qi + 2;
  for (int tk = 0; tk < NT; ++tk) {
    const int kv0 = tk * 64;
    __builtin_amdgcn_s_barrier();  // WAR: prior tile's LDS reads consumed
    stageKV(kv0);
    asm volatile("s_waitcnt vmcnt(0)" ::: "memory");
    __builtin_amdgcn_s_barrier();  // all waves' loads landed

    // S^T = K Q^T : sacc[kb][r] = S[k = kv0+kb*32+(r&3)+8(r>>2)+4hi][q = qrow]
    f32x16 sacc[2] = {};
#pragma unroll
    for (int kb = 0; kb < 2; ++kb) {
      const int krow = kb * 32 + lq;
#pragma unroll
      for (int s = 0; s < 8; ++s) {
        const short8 kf =
            *(const short8*)&Ks[krow * 128 + (((s * 2 + hi) ^ (lq & 7)) << 3)];
        sacc[kb] = MFMA32(kf, qf[s], sacc[kb]);
      }
    }

    // mask + scale + per-lane max (q fixed per lane)
    float mx = -1e30f;
#pragma unroll
    for (int kb = 0; kb < 2; ++kb)
#pragma unroll
      for (int r = 0; r < 16; ++r) {
        float sv = sacc[kb][r] * 0.08838834764831845f;
        const int k = kv0 + kb * 32 + (r & 3) + 8 * (r >> 2) + 4 * hi;
        if (k > qrow) sv = -1e30f;
        sacc[kb][r] = sv;
        mx = fmaxf(mx, sv);
      }
    mx = fmaxf(mx, __shfl_xor(mx, 32));
    const float mnew = fmaxf(mrun, mx);
    const float alpha = __expf(mrun - mnew);
    mrun = mnew;

    float rs = 0.f;
#pragma unroll
    for (int kb = 0; kb < 2; ++kb)
#pragma unroll
      for (int g = 0; g < 4; ++g) {
        s16x4 pk;
#pragma unroll
        for (int j = 0; j < 4; ++j) {
          const float pv = __expf(sacc[kb][g * 4 + j] - mnew);
          rs += pv;
          pk[j] = bf16_bits(pv);
        }
        // chunk c = kb*4+g holds k in [8c,8c+8); hi picks the 8B half
        *(s16x4*)(Psw + lq * 128 + (((kb * 4 + g) ^ (lq & 7)) << 4) + hi * 8) = pk;
      }
    rs += __shfl_xor(rs, 32);
    lrun = lrun * alpha + rs;
#pragma unroll
    for (int db = 0; db < 4; ++db)
#pragma unroll
      for (int r = 0; r < 16; ++r) oacc[db][r] *= alpha;

    // intra-wave P exchange: drain DS queue, pin order (rule #18)
    asm volatile("s_waitcnt lgkmcnt(0)" ::: "memory");
    __builtin_amdgcn_sched_barrier(0);

    // O^T += V^T P^T : A=V^T rows d (32-blocks), B=P^T cols q
#pragma unroll
    for (int ks = 0; ks < 4; ++ks) {
      const short8 pf =
          *(const short8*)(Psw + lq * 128 + (((ks * 2 + hi) ^ (lq & 7)) << 4));
#pragma unroll
      for (int db = 0; db < 4; ++db) {
        const int vrow = db * 32 + lq;
        const short8 vf =
            *(const short8*)&Vs[vrow * 64 + (((ks * 2 + hi) ^ (lq & 7)) << 3)];
        oacc[db] = MFMA32(vf, pf, oacc[db]);
      }
    }
  }

  // epilogue: O[q=qrow][d = db*32 + 8g + 4hi + j]; 16 x 8B stores
  const float inv = 1.0f / lrun;
  __hip_bfloat16* obase = Ob + (size_t)(b * S + qrow) * D + h * HD;
#pragma unroll
  for (int db = 0; db < 4; ++db)
#pragma unroll
    for (int g = 0; g < 4; ++g) {
      s16x4 o;
#pragma unroll
      for (int j = 0; j < 4; ++j)
        o[j] = bf16_bits(finite_or(oacc[db][g * 4 + j] * inv, 300.0f));
      *(s16x4*)(obase + db * 32 + 8 * g + 4 * hi) = o;
    }
}

// ---------------------------------------------------------------------------
extern "C" void kernel_launch(void* const* d_in, const int* in_sizes, int n_in,
                              void* d_out, int out_size, void* d_ws, size_t ws_size,
                              hipStream_t stream)
{
  const float* q  = (const float*)d_in[0];
  const float* k  = (const float*)d_in[1];
  const float* v  = (const float*)d_in[2];
  const float* Wq = (const float*)d_in[3];
  const float* bq = (const float*)d_in[4];
  const float* Wk = (const float*)d_in[5];
  const float* bk = (const float*)d_in[6];
  const float* Wv = (const float*)d_in[7];
  const float* bv = (const float*)d_in[8];
  const float* Wo = (const float*)d_in[9];
  const float* bo = (const float*)d_in[10];

  char* wsb = (char*)d_ws;
  const size_t MB = 1024 * 1024;
  __hip_bfloat16* Qw  = (__hip_bfloat16*)(wsb + 0 * MB);
  __hip_bfloat16* Kw  = (__hip_bfloat16*)(wsb + 16 * MB);
  __hip_bfloat16* Vt2 = (__hip_bfloat16*)(wsb + 32 * MB);  // [2048][4096] direct-transposed
  __hip_bfloat16* xqb = (__hip_bfloat16*)(wsb + 48 * MB);
  __hip_bfloat16* xkb = (__hip_bfloat16*)(wsb + 64 * MB);
  __hip_bfloat16* xvb = (__hip_bfloat16*)(wsb + 80 * MB);
  __hip_bfloat16* Wqb = (__hip_bfloat16*)(wsb + 96 * MB);
  __hip_bfloat16* Wkb = (__hip_bfloat16*)(wsb + 104 * MB);
  __hip_bfloat16* Wvb = (__hip_bfloat16*)(wsb + 112 * MB);
  __hip_bfloat16* Wob = (__hip_bfloat16*)(wsb + 120 * MB);
  __hip_bfloat16* Ow  = xkb;  // xk dead after QK GEMM

  // 0) convert all f32 operands to bf16
  cvt_kernel<<<dim3(1024, 7), 256, 0, stream>>>(
      q, k, v, Wq, Wk, Wv, Wo, xqb, xkb, xvb, Wqb, Wkb, Wvb, Wob);
  // 1) fused Q,K projections + direct-transposed V projection (768 blocks)
  gemm_qkvvt_kernel<<<dim3(768), 512, 0, stream>>>(
      xqb, xkb, xvb, Wqb, Wkb, Wvb, bq, bk, bv, Qw, Kw, Vt2);
  // 2) causal flash attention -> Ow (bf16); 512 blocks of 128 q, 32x32 frags
  attn_kernel<<<dim3(512), 256, 0, stream>>>(Qw, Kw, Vt2, Ow);
  // 3) output projection -> d_out (f32)
  gemm_out_kernel<<<dim3(8, 32), 512, 0, stream>>>(
      Ow, Wob, bo, (float*)d_out);
}

// Round 22
// 269.314 us; speedup vs baseline: 1.0267x; 1.0267x over previous
//
#include <hip/hip_runtime.h>
#include <hip/hip_bf16.h>

typedef __attribute__((ext_vector_type(8))) short short8;
typedef __attribute__((ext_vector_type(4))) short s16x4;
typedef __attribute__((ext_vector_type(4))) float f32x4;

#define MFMA_BF16(A, B, C) __builtin_amdgcn_mfma_f32_16x16x32_bf16(A, B, C, 0, 0, 0)

// async global->LDS, 16B per lane. LDS dest is wave-uniform base + lane*16.
__device__ __forceinline__ void gload_lds16(const __hip_bfloat16* g, __hip_bfloat16* l) {
  __builtin_amdgcn_global_load_lds(
      (const __attribute__((address_space(1))) unsigned int*)g,
      (__attribute__((address_space(3))) unsigned int*)l, 16, 0, 0);
}

// NaN/Inf tripwire (fast-math-immune): finite -> x, else -> repl.
__device__ __forceinline__ float finite_or(float x, float repl) {
  unsigned u;
  __builtin_memcpy(&u, &x, 4);
  return ((u & 0x7f800000u) == 0x7f800000u) ? repl : x;
}

__device__ __forceinline__ short bf16_bits(float x) {
  __hip_bfloat16 b = __float2bfloat16(x);
  short s;
  __builtin_memcpy(&s, &b, 2);
  return s;
}

__device__ __forceinline__ short8 pack8(f32x4 a, f32x4 b) {
  short8 r;
  r[0] = bf16_bits(a[0]); r[1] = bf16_bits(a[1]);
  r[2] = bf16_bits(a[2]); r[3] = bf16_bits(a[3]);
  r[4] = bf16_bits(b[0]); r[5] = bf16_bits(b[1]);
  r[6] = bf16_bits(b[2]); r[7] = bf16_bits(b[3]);
  return r;
}

// ---------------------------------------------------------------------------
// f32 -> bf16 bulk conversion.
// ---------------------------------------------------------------------------
__global__ __launch_bounds__(256) void cvt_kernel(
    const float* x0, const float* x1, const float* x2,
    const float* w0, const float* w1, const float* w2, const float* w3,
    __hip_bfloat16* y0, __hip_bfloat16* y1, __hip_bfloat16* y2,
    __hip_bfloat16* u0, __hip_bfloat16* u1, __hip_bfloat16* u2, __hip_bfloat16* u3)
{
  const int z = blockIdx.y;
  const float* s = z == 0 ? x0 : z == 1 ? x1 : z == 2 ? x2
                 : z == 3 ? w0 : z == 4 ? w1 : z == 5 ? w2 : w3;
  __hip_bfloat16* d = z == 0 ? y0 : z == 1 ? y1 : z == 2 ? y2
                    : z == 3 ? u0 : z == 4 ? u1 : z == 5 ? u2 : u3;
  const size_t n = (z < 3) ? (size_t)8388608 : (size_t)4194304;
  const size_t stride = (size_t)gridDim.x * 256 * 8;
  for (size_t i = ((size_t)blockIdx.x * 256 + threadIdx.x) * 8; i < n; i += stride) {
    f32x4 a = *(const f32x4*)(s + i);
    f32x4 b = *(const f32x4*)(s + i + 4);
    *(short8*)((short*)d + i) = pack8(a, b);
  }
}

// ---------------------------------------------------------------------------
// Pipelined GEMM body (T3+T4): 128x256 tile, BK=64, 8 waves, ring-3 LDS,
// counted vmcnt(6). R17/R19-verified structure.
// ---------------------------------------------------------------------------
#define GBUF 24576

__device__ __forceinline__ void stage_A(const __hip_bfloat16* Ab, __hip_bfloat16* bufA,
                                        int kcol, int t, int wave) {
#pragma unroll
  for (int r = 0; r < 2; ++r) {
    const int ci = r * 512 + t;
    const int row = ci >> 3, c = ci & 7;
    const int sc = c ^ (row & 7);
    gload_lds16(Ab + (size_t)row * 2048 + kcol + sc * 8, bufA + r * 4096 + wave * 512);
  }
}
__device__ __forceinline__ void stage_Br(const __hip_bfloat16* Bb, __hip_bfloat16* bufB,
                                         int kcol, int t, int wave, int r) {
  const int ci = r * 512 + t;
  const int row = ci >> 3, c = ci & 7;
  const int sc = c ^ (row & 7);
  gload_lds16(Bb + (size_t)row * 2048 + kcol + sc * 8, bufB + r * 4096 + wave * 512);
}

template <typename OutT, bool BIAS_ROW>
__device__ __forceinline__ void gemm8p_body(
    const __hip_bfloat16* __restrict__ A, const __hip_bfloat16* __restrict__ Bt,
    const float* __restrict__ bias, OutT* __restrict__ C,
    int m0, int n0, int N, float trip, __hip_bfloat16* sm)
{
  constexpr int K = 2048, NT = K / 64;
  const int t = threadIdx.x, wave = t >> 6, lane = t & 63;
  const int ll = lane & 15, lg = lane >> 4;
  const int wmB = (wave >> 2) * 64, wnB = (wave & 3) * 64;
  const __hip_bfloat16* Ab = A + (size_t)m0 * K;
  const __hip_bfloat16* Bb = Bt + (size_t)n0 * K;

  f32x4 acc[4][4] = {};

  stage_A(Ab, sm, 0, t, wave);
  stage_Br(Bb, sm + 8192, 0, t, wave, 0);
  stage_Br(Bb, sm + 8192, 0, t, wave, 1);
  stage_Br(Bb, sm + 8192, 0, t, wave, 2);
  stage_Br(Bb, sm + 8192, 0, t, wave, 3);
  stage_A(Ab, sm + GBUF, 64, t, wave);
  stage_Br(Bb, sm + GBUF + 8192, 64, t, wave, 0);
  stage_Br(Bb, sm + GBUF + 8192, 64, t, wave, 1);
  stage_Br(Bb, sm + GBUF + 8192, 64, t, wave, 2);
  stage_Br(Bb, sm + GBUF + 8192, 64, t, wave, 3);
  asm volatile("s_waitcnt vmcnt(6)" ::: "memory");
  __builtin_amdgcn_s_barrier();

  for (int i = 0; i < NT; ++i) {
    const __hip_bfloat16* bufA = sm + (i % 3) * GBUF;
    const __hip_bfloat16* bufB = bufA + 8192;
    const bool pf = (i + 2 < NT);
    __hip_bfloat16* pA = sm + ((i + 2) % 3) * GBUF;
    const int pk = (i + 2) * 64;

#pragma unroll
    for (int kk = 0; kk < 2; ++kk) {
      short8 af[4], bf[4];
#pragma unroll
      for (int f = 0; f < 4; ++f) {
        const int ar = wmB + f * 16 + ll;
        af[f] = *(const short8*)&bufA[ar * 64 + (((kk * 4 + lg) ^ (ar & 7)) << 3)];
        const int br = wnB + f * 16 + ll;
        bf[f] = *(const short8*)&bufB[br * 64 + (((kk * 4 + lg) ^ (br & 7)) << 3)];
      }
      if (pf) {
        if (kk == 0) {
          stage_A(Ab, pA, pk, t, wave);
          stage_Br(Bb, pA + 8192, pk, t, wave, 0);
        } else {
          stage_Br(Bb, pA + 8192, pk, t, wave, 1);
          stage_Br(Bb, pA + 8192, pk, t, wave, 2);
          stage_Br(Bb, pA + 8192, pk, t, wave, 3);
        }
      }
      asm volatile("s_waitcnt lgkmcnt(0)" ::: "memory");
      __builtin_amdgcn_sched_barrier(0);
      __builtin_amdgcn_s_setprio(1);
#pragma unroll
      for (int mi = 0; mi < 4; ++mi)
#pragma unroll
        for (int ni = 0; ni < 4; ++ni)
          acc[mi][ni] = MFMA_BF16(af[mi], bf[ni], acc[mi][ni]);
      __builtin_amdgcn_s_setprio(0);
      __builtin_amdgcn_sched_barrier(0);
    }

    const int rem = NT - 1 - i;
    if (rem >= 2) {
      asm volatile("s_waitcnt vmcnt(6)" ::: "memory");
      __builtin_amdgcn_s_barrier();
    } else if (rem == 1) {
      asm volatile("s_waitcnt vmcnt(0)" ::: "memory");
      __builtin_amdgcn_s_barrier();
    }
  }

#pragma unroll
  for (int mi = 0; mi < 4; ++mi)
#pragma unroll
    for (int ni = 0; ni < 4; ++ni) {
      const int col = n0 + wnB + ni * 16 + ll;
      const float bcol = BIAS_ROW ? 0.f : bias[col];
#pragma unroll
      for (int j = 0; j < 4; ++j) {
        const int row = m0 + wmB + mi * 16 + lg * 4 + j;
        const float bv = BIAS_ROW ? bias[row] : bcol;
        const float val = finite_or(acc[mi][ni][j] + bv, trip);
        if constexpr (__is_same(OutT, float))
          C[(size_t)row * N + col] = val;
        else
          C[(size_t)row * N + col] = __float2bfloat16(val);
      }
    }
}

// Fused launch: blocks 0..511 = Q,K projections; 512..767 = V^T projection.
__global__ __launch_bounds__(512) void gemm_qkvvt_kernel(
    const __hip_bfloat16* xq, const __hip_bfloat16* xk, const __hip_bfloat16* xv,
    const __hip_bfloat16* Wq, const __hip_bfloat16* Wk, const __hip_bfloat16* Wv,
    const float* bq, const float* bk, const float* bv,
    __hip_bfloat16* Q, __hip_bfloat16* K, __hip_bfloat16* Vt2)
{
  __shared__ __align__(16) __hip_bfloat16 sm[3 * GBUF];
  const int L = (int)blockIdx.x;
  if (L < 512) {
    const int z = L & 1;
    const int r = L >> 1;            // 0..255
    const int n0 = (r & 7) * 256;    // N=2048 -> 8 n-tiles
    const int m0 = (r >> 3) * 128;   // M=4096 -> 32 m-tiles
    gemm8p_body<__hip_bfloat16, false>(z ? xk : xq, z ? Wk : Wq, z ? bk : bq,
                                       z ? K : Q, m0, n0, 2048, 20000.0f, sm);
  } else {
    const int r = L - 512;           // 0..255
    const int n0 = (r & 15) * 256;   // N=4096 -> 16 n-tiles
    const int m0 = (r >> 4) * 128;   // M=2048 -> 16 m-tiles
    gemm8p_body<__hip_bfloat16, true>(Wv, xv, bv, Vt2, m0, n0, 4096, 30000.0f, sm);
  }
}

__global__ __launch_bounds__(512) void gemm_out_kernel(
    const __hip_bfloat16* A, const __hip_bfloat16* W, const float* b, float* C)
{
  __shared__ __align__(16) __hip_bfloat16 sm[3 * GBUF];
  gemm8p_body<float, false>(A, W, b, C, (int)blockIdx.y * 128,
                            (int)blockIdx.x * 256, 2048, 50000.0f, sm);
}

// ---------------------------------------------------------------------------
// Causal flash attention (R20-verified best): R8 per-tile body, single-buffered
// K/V (40 KiB LDS -> 4 blocks/CU), 1024 single-qi blocks; under id%8
// round-robin each CU's 4 blocks share bh and get qi {a,15-a,16+a,31-a}
// -> exactly 66 tiles per CU (uniform by construction).
// ---------------------------------------------------------------------------
__global__ __launch_bounds__(256) void attn_kernel(
    const __hip_bfloat16* __restrict__ Qb, const __hip_bfloat16* __restrict__ Kb,
    const __hip_bfloat16* __restrict__ Vt, __hip_bfloat16* __restrict__ Ob)
{
  constexpr int S = 2048, D = 2048, HD = 128;
  __shared__ __align__(16) __hip_bfloat16 Ks[64 * 128];  // chunk ^= row&7
  __shared__ __align__(16) __hip_bfloat16 Vs[128 * 64];  // chunk ^= d&7
  __shared__ __align__(16) short Ps[4][16 * 64];         // P^T [q][k], chunk ^= q&7

  const int t = threadIdx.x, wave = t >> 6, lane = t & 63;
  const int lg = lane >> 4, ll = lane & 15;
  const int L = (int)blockIdx.x;                   // 0..1023
  const int bh = ((L & 7) << 2) | ((L >> 3) & 3);  // same for L, L+256, ... (XCD-grouped)
  const int p = L >> 5;                            // 0..31
  const int a = p & 7, bq_ = p >> 3;
  const int qi = (bq_ == 0) ? a : (bq_ == 1) ? 15 - a
               : (bq_ == 2) ? 16 + a : 31 - a;     // CU set {a,15-a,16+a,31-a}: 66 tiles
  const int b = bh >> 4, h = bh & 15;
  const int q0 = qi * 64;
  const int qrow = q0 + wave * 16 + ll;
  char* const Psw = (char*)&Ps[wave][0];

  auto stageKV = [&](int kv0) {
#pragma unroll
    for (int r = 0; r < 4; ++r) {
      const int s = r * 256 + t;
      const int row = s >> 4, ch = s & 15;
      const int sc = ch ^ (row & 7);
      gload_lds16(Kb + (size_t)(b * S + kv0 + row) * D + h * HD + sc * 8,
                  Ks + r * 2048 + wave * 512);
    }
#pragma unroll
    for (int r = 0; r < 4; ++r) {
      const int s = r * 256 + t;
      const int d = s >> 3, ch = s & 7;
      const int sc = ch ^ (d & 7);
      gload_lds16(Vt + (size_t)(h * HD + d) * (2 * S) + b * S + kv0 + sc * 8,
                  Vs + r * 2048 + wave * 512);
    }
  };

  // Q fragments (B-operand): row=q, elems d=lg*8+e per kc
  short8 qf[4];
  const __hip_bfloat16* qptr = Qb + (size_t)(b * S + qrow) * D + h * HD + lg * 8;
#pragma unroll
  for (int kc = 0; kc < 4; ++kc) qf[kc] = *(const short8*)(qptr + kc * 32);

  f32x4 oacc[8] = {};
  float mrun = -1e30f, lrun = 0.f;

  for (int tk = 0; tk <= qi; ++tk) {
    const int kv0 = tk * 64;
    __builtin_amdgcn_s_barrier();  // WAR: all waves' prior-tile LDS reads consumed
    stageKV(kv0);
    asm volatile("s_waitcnt vmcnt(0)" ::: "memory");  // my loads landed
    __builtin_amdgcn_s_barrier();                     // everyone's loads landed

    // S^T = K Q^T : sacc[nf][j] = S[k = kv0+nf*16+lg*4+j][q = qrow]
    f32x4 sacc[4] = {};
#pragma unroll
    for (int nf = 0; nf < 4; ++nf) {
      const int krow = nf * 16 + ll;
#pragma unroll
      for (int kc = 0; kc < 4; ++kc) {
        const int sw = (kc * 4 + lg) ^ (krow & 7);
        const short8 kf = *(const short8*)&Ks[krow * 128 + sw * 8];
        sacc[nf] = MFMA_BF16(kf, qf[kc], sacc[nf]);
      }
    }

    // per-lane softmax; row-reduce = 2 shfl_xor
    float sv[4][4];
    float mx = -1e30f;
#pragma unroll
    for (int nf = 0; nf < 4; ++nf)
#pragma unroll
      for (int j = 0; j < 4; ++j) {
        float s = sacc[nf][j] * 0.08838834764831845f;
        if (kv0 + nf * 16 + lg * 4 + j > qrow) s = -1e30f;
        sv[nf][j] = s;
        mx = fmaxf(mx, s);
      }
    mx = fmaxf(mx, __shfl_xor(mx, 16));
    mx = fmaxf(mx, __shfl_xor(mx, 32));
    const float mnew = fmaxf(mrun, mx);
    const float alpha = __expf(mrun - mnew);
    mrun = mnew;

    float rs = 0.f;
#pragma unroll
    for (int nf = 0; nf < 4; ++nf) {
      s16x4 pk;
#pragma unroll
      for (int j = 0; j < 4; ++j) {
        const float pv = __expf(sv[nf][j] - mnew);
        rs += pv;
        pk[j] = bf16_bits(pv);
      }
      const int chunk = (nf * 2 + (lg >> 1)) ^ (ll & 7);
      *(s16x4*)(Psw + ll * 128 + chunk * 16 + (lg & 1) * 8) = pk;
    }
    rs += __shfl_xor(rs, 16);
    rs += __shfl_xor(rs, 32);
    lrun = lrun * alpha + rs;
#pragma unroll
    for (int df = 0; df < 8; ++df)
#pragma unroll
      for (int j = 0; j < 4; ++j) oacc[df][j] *= alpha;

    // intra-wave P exchange: drain DS queue, pin order (rule #18)
    asm volatile("s_waitcnt lgkmcnt(0)" ::: "memory");
    __builtin_amdgcn_sched_barrier(0);

    // O^T += V^T P^T
#pragma unroll
    for (int ks = 0; ks < 2; ++ks) {
      const int pchunk = (ks * 4 + lg) ^ (ll & 7);
      const short8 pf8 = *(const short8*)(Psw + ll * 128 + pchunk * 16);
#pragma unroll
      for (int df = 0; df < 8; ++df) {
        const int vrow = df * 16 + ll;
        const int sw = (ks * 4 + lg) ^ (vrow & 7);
        const short8 vf = *(const short8*)&Vs[vrow * 64 + sw * 8];
        oacc[df] = MFMA_BF16(vf, pf8, oacc[df]);
      }
    }
  }

  // epilogue: O[q][d], d = df*16+lg*4+j ; 8B vector stores
  const float inv = 1.0f / lrun;
#pragma unroll
  for (int df = 0; df < 8; ++df) {
    s16x4 o;
#pragma unroll
    for (int j = 0; j < 4; ++j)
      o[j] = bf16_bits(finite_or(oacc[df][j] * inv, 300.0f));
    *(s16x4*)(Ob + (size_t)(b * S + qrow) * D + h * HD + df * 16 + lg * 4) = o;
  }
}

// ---------------------------------------------------------------------------
extern "C" void kernel_launch(void* const* d_in, const int* in_sizes, int n_in,
                              void* d_out, int out_size, void* d_ws, size_t ws_size,
                              hipStream_t stream)
{
  const float* q  = (const float*)d_in[0];
  const float* k  = (const float*)d_in[1];
  const float* v  = (const float*)d_in[2];
  const float* Wq = (const float*)d_in[3];
  const float* bq = (const float*)d_in[4];
  const float* Wk = (const float*)d_in[5];
  const float* bk = (const float*)d_in[6];
  const float* Wv = (const float*)d_in[7];
  const float* bv = (const float*)d_in[8];
  const float* Wo = (const float*)d_in[9];
  const float* bo = (const float*)d_in[10];

  char* wsb = (char*)d_ws;
  const size_t MB = 1024 * 1024;
  __hip_bfloat16* Qw  = (__hip_bfloat16*)(wsb + 0 * MB);
  __hip_bfloat16* Kw  = (__hip_bfloat16*)(wsb + 16 * MB);
  __hip_bfloat16* Vt2 = (__hip_bfloat16*)(wsb + 32 * MB);  // [2048][4096] direct-transposed
  __hip_bfloat16* xqb = (__hip_bfloat16*)(wsb + 48 * MB);
  __hip_bfloat16* xkb = (__hip_bfloat16*)(wsb + 64 * MB);
  __hip_bfloat16* xvb = (__hip_bfloat16*)(wsb + 80 * MB);
  __hip_bfloat16* Wqb = (__hip_bfloat16*)(wsb + 96 * MB);
  __hip_bfloat16* Wkb = (__hip_bfloat16*)(wsb + 104 * MB);
  __hip_bfloat16* Wvb = (__hip_bfloat16*)(wsb + 112 * MB);
  __hip_bfloat16* Wob = (__hip_bfloat16*)(wsb + 120 * MB);
  __hip_bfloat16* Ow  = xkb;  // xk dead after QK GEMM

  // 0) convert all f32 operands to bf16
  cvt_kernel<<<dim3(1024, 7), 256, 0, stream>>>(
      q, k, v, Wq, Wk, Wv, Wo, xqb, xkb, xvb, Wqb, Wkb, Wvb, Wob);
  // 1) fused Q,K projections + direct-transposed V projection (768 blocks)
  gemm_qkvvt_kernel<<<dim3(768), 512, 0, stream>>>(
      xqb, xkb, xvb, Wqb, Wkb, Wvb, bq, bk, bv, Qw, Kw, Vt2);
  // 2) causal flash attention -> Ow (bf16); 1024 blocks, 4/CU, uniform 66 tiles/CU
  attn_kernel<<<dim3(1024), 256, 0, stream>>>(Qw, Kw, Vt2, Ow);
  // 3) output projection -> d_out (f32)
  gemm_out_kernel<<<dim3(8, 32), 512, 0, stream>>>(
      Ow, Wob, bo, (float*)d_out);
}